// Round 6
// baseline (1073.722 us; speedup 1.0000x reference)
//
#include <hip/hip_runtime.h>
#include <math.h>

#define BB 256
#define TT 1024
#define KK 128
#define CHUNK 8
#define NCHUNK (TT / CHUNK)  // 128

typedef float f4 __attribute__((ext_vector_type(4)));
typedef short s8 __attribute__((ext_vector_type(8)));

#define MFMA16 __builtin_amdgcn_mfma_f32_16x16x32_bf16

__global__ void zero_out_kernel(float* out) { out[0] = 0.0f; }

__device__ __forceinline__ unsigned short bf16r(float x) {
    unsigned u = __float_as_uint(x);
    return (unsigned short)((u + 0x7FFFu + ((u >> 16) & 1u)) >> 16);
}

// B-fragment of exp(trans) for tile (kt, nt), 16x16x32 bf16 layout:
// B[k][n]: n = lane&15, k = (lane>>4)*8 + i3.  Global i = 32*kt + k, j = 16*nt + n.
__device__ __forceinline__ s8 load_E(const float* __restrict__ trans, int kt, int nt, int lane) {
    s8 f;
    const float* base = trans + (size_t)(32 * kt + ((lane >> 4) << 3)) * KK + 16 * nt + (lane & 15);
#pragma unroll
    for (int i3 = 0; i3 < 8; ++i3)
        f[i3] = (short)bf16r(expf(base[(size_t)i3 * KK]));
    return f;
}

#define DECLE(KT) \
    s8 E##KT##_0 = load_E(trans, KT, 0, l); \
    s8 E##KT##_1 = load_E(trans, KT, 1, l); \
    s8 E##KT##_2 = load_E(trans, KT, 2, l); \
    s8 E##KT##_3 = load_E(trans, KT, 3, l); \
    s8 E##KT##_4 = load_E(trans, KT, 4, l); \
    s8 E##KT##_5 = load_E(trans, KT, 5, l); \
    s8 E##KT##_6 = load_E(trans, KT, 6, l); \
    s8 E##KT##_7 = load_E(trans, KT, 7, l);

// One nt-tile: 4-deep MFMA chain over kt, then epilogue on row 0 (lanes 0-15, reg .x)
#define DO_NT(NT) { \
    f4 acc = (f4){0.f, 0.f, 0.f, 0.f}; \
    acc = MFMA16(a0, E0_##NT, acc, 0, 0, 0); \
    acc = MFMA16(a1, E1_##NT, acc, 0, 0, 0); \
    acc = MFMA16(a2, E2_##NT, acc, 0, 0, 0); \
    acc = MFMA16(a3, E3_##NT, acc, 0, 0, 0); \
    float xv = eb[(s << 7) + (NT << 4) + jl]; \
    float pc = msk ? acc.x * xv * sc : pp[NT]; \
    pp[NT] = pc; \
    if (l16) pzw[(NT << 4) + l] = bf16r(pc); \
}

// One block per batch, ONE wave (64 threads), 256 blocks -> 256 CUs.
// Forward recursion in exp space via MFMA: z(1x128) = p(1x128) . E(128x128),
// E = exp(trans) as 32 named bf16 B-fragments (128 VGPRs, reg-resident at
// __launch_bounds__(64,1)). p stored bf16 in LDS (256 B), read back directly
// as A-fragments (row 0 only; rows 1-15 read a zeroed pad -> exact zeros).
// Renorm: exact pow2 from exponent of p_prev[0] (wave-uniform via readlane).
__global__ __launch_bounds__(64, 1) void crf_kernel(
    const float* __restrict__ inputs,      // B*T*K fp32
    const float* __restrict__ trans,       // K*K fp32
    const int* __restrict__ tags,          // B*T int32 view
    const int* __restrict__ mask,          // B*T int32
    float* __restrict__ out)               // scalar
{
    __shared__ __align__(16) unsigned short pzb[2][144];   // 128 bf16 p + 16 zero pad
    __shared__ __align__(16) float ebuf[2][CHUNK * KK];    // X = exp(emissions)
    __shared__ float mbuf[2][CHUNK];

    const int l  = threadIdx.x;   // 0..63
    const int jl = l & 15;
    const int b  = blockIdx.x;
    const bool l16 = (l < 16);
    const bool act = (jl == 0);             // lanes supplying A row 0
    const int row8 = (l >> 4) << 3;
    const int ia0 = act ? row8       : 128; // zero pad for m!=0 rows
    const int ia1 = act ? 32 + row8  : 128;
    const int ia2 = act ? 64 + row8  : 128;
    const int ia3 = act ? 96 + row8  : 128;

    const float* binp = inputs + (size_t)b * TT * KK;
    const int* bmask  = mask + (size_t)b * TT;
    const int* btags  = tags + (size_t)b * TT;

    // ---- E fragments: 32 named s8 (spill-proof), bf16 ----
    DECLE(0) DECLE(1) DECLE(2) DECLE(3)

    // zero pad region (harness poisons LDS)
    if (l16) { pzb[0][128 + l] = 0; pzb[1][128 + l] = 0; }

    // ---- stage chunk 0: X = exp(e) ----
#pragma unroll
    for (int k = 0; k < 4; ++k) {
        float4 e = ((const float4*)binp)[l + 64 * k];
        e.x = __expf(e.x); e.y = __expf(e.y); e.z = __expf(e.z); e.w = __expf(e.w);
        ((float4*)ebuf[0])[l + 64 * k] = e;
    }
    if (l < CHUNK) mbuf[0][l] = (float)bmask[l];
    __syncthreads();

    // ---- t = 0: p = exp(alpha0) = X[0][j]; lane l (0-15) holds p[16*nt + l] ----
    float pp[8];
#pragma unroll
    for (int nt = 0; nt < 8; ++nt)
        pp[nt] = l16 ? ebuf[0][(nt << 4) + l] : 0.0f;
    if (l16) {
#pragma unroll
        for (int nt = 0; nt < 8; ++nt)
            pzb[0][(nt << 4) + l] = bf16r(pp[nt]);
    }
    int m_int = 0;
    __syncthreads();

    for (int c = 0; c < NCHUNK; ++c) {
        // prefetch next emission chunk (exp applied at store)
        float4 ep0, ep1, ep2, ep3; int mpre = 0;
        if (c + 1 < NCHUNK) {
            const float4* src = (const float4*)(binp + (size_t)(c + 1) * CHUNK * KK);
            ep0 = src[l]; ep1 = src[l + 64]; ep2 = src[l + 128]; ep3 = src[l + 192];
            if (l < CHUNK) mpre = bmask[(c + 1) * CHUNK + l];
        }
        const float* eb = ebuf[c & 1];
        const float* mb = mbuf[c & 1];
        const int s0 = (c == 0) ? 1 : 0;
        for (int s = s0; s < CHUNK; ++s) {
            const int t = c * CHUNK + s;
            const unsigned short* pzr = pzb[(t - 1) & 1];
            unsigned short* pzw = pzb[t & 1];
            // uniform renorm scale from exponent of p_prev[0] (lane 0's pp[0])
            int pb0 = __builtin_amdgcn_readlane(__float_as_int(pp[0]), 0);
            int E0 = ((pb0 >> 23) & 255) - 127;
            float sc = __uint_as_float((unsigned)(127 - E0) << 23);   // 2^-E0
            float mi = mb[s];
            bool msk = (mi != 0.0f);
            // A-fragments: p_prev as bf16 straight from LDS (row 0 lanes real, rest zero)
            s8 a0 = *(const s8*)&pzr[ia0];
            s8 a1 = *(const s8*)&pzr[ia1];
            s8 a2 = *(const s8*)&pzr[ia2];
            s8 a3 = *(const s8*)&pzr[ia3];
            DO_NT(0) DO_NT(1) DO_NT(2) DO_NT(3)
            DO_NT(4) DO_NT(5) DO_NT(6) DO_NT(7)
            m_int += msk ? E0 : 0;
            __syncthreads();
        }
        if (c + 1 < NCHUNK) {
            ep0.x = __expf(ep0.x); ep0.y = __expf(ep0.y); ep0.z = __expf(ep0.z); ep0.w = __expf(ep0.w);
            ep1.x = __expf(ep1.x); ep1.y = __expf(ep1.y); ep1.z = __expf(ep1.z); ep1.w = __expf(ep1.w);
            ep2.x = __expf(ep2.x); ep2.y = __expf(ep2.y); ep2.z = __expf(ep2.z); ep2.w = __expf(ep2.w);
            ep3.x = __expf(ep3.x); ep3.y = __expf(ep3.y); ep3.z = __expf(ep3.z); ep3.w = __expf(ep3.w);
            float4* dst = (float4*)ebuf[(c + 1) & 1];
            dst[l] = ep0; dst[l + 64] = ep1; dst[l + 128] = ep2; dst[l + 192] = ep3;
            if (l < CHUNK) mbuf[(c + 1) & 1][l] = (float)mpre;
            __syncthreads();
        }
    }

    // ---- denominator: LSE_j alpha_j = m*ln2 + log(sum_j p_j)  (common m) ----
    float psum = 0.0f;
#pragma unroll
    for (int nt = 0; nt < 8; ++nt) psum += pp[nt];   // lanes >=16 hold exact zeros
#pragma unroll
    for (int o = 1; o < 64; o <<= 1) psum += __shfl_xor(psum, o);
    float den = (float)m_int * 0.69314718055994531f + logf(psum);

    // ---- numerator (gold-path score), one wave ----
    float numpart = 0.0f, maskpart = 0.0f;
#pragma unroll
    for (int kk = 0; kk < TT / 64; ++kk) {
        int t = l + 64 * kk;
        int tg = btags[t];
        float mf = (float)bmask[t];
        maskpart += mf;
        if (t < TT - 1) {
            int tg1   = btags[t + 1];
            float mf1 = (float)bmask[t + 1];
            numpart += trans[tg * KK + tg1] * mf1;
            numpart += binp[(size_t)t * KK + tg] * mf;
        }
    }
#pragma unroll
    for (int o = 1; o < 64; o <<= 1) numpart += __shfl_xor(numpart, o);
#pragma unroll
    for (int o = 1; o < 64; o <<= 1) maskpart += __shfl_xor(maskpart, o);
    if (l == 0) {
        int last_idx = (int)maskpart - 1;
        int ltag = btags[last_idx];
        float num = numpart + binp[(size_t)(TT - 1) * KK + ltag] * (float)bmask[TT - 1];
        atomicAdd(out, num - den);
    }
}

extern "C" void kernel_launch(void* const* d_in, const int* in_sizes, int n_in,
                              void* d_out, int out_size, void* d_ws, size_t ws_size,
                              hipStream_t stream) {
    const float* inputs = (const float*)d_in[0];
    const float* trans  = (const float*)d_in[1];
    const int* tagsp    = (const int*)d_in[2];
    const int* maskp    = (const int*)d_in[3];
    float* out          = (float*)d_out;
    zero_out_kernel<<<1, 1, 0, stream>>>(out);
    crf_kernel<<<BB, 64, 0, stream>>>(inputs, trans, tagsp, maskp, out);
}